// Round 1
// baseline (855.541 us; speedup 1.0000x reference)
//
#include <hip/hip_runtime.h>
#include <hip/hip_bf16.h>

typedef __attribute__((ext_vector_type(8))) short short8;
typedef __attribute__((ext_vector_type(4))) float f32x4;

#define LRELU_SLOPE 0.2f
#define ACT_GAIN 1.41421356237309515f
#define WG_RGB 0.04419417382415922f   // 1/sqrt(512)

// ---------------- P1: styles  s = ws[:,0]@caw^T + cab ;  s2 = (ws[:,1]@raw^T + rab)*wg
__global__ void k_styles(const float* __restrict__ wsin,
                         const float* __restrict__ caw, const float* __restrict__ cab,
                         const float* __restrict__ raw_, const float* __restrict__ rab,
                         float* __restrict__ sbuf, float* __restrict__ s2buf) {
    int b = blockIdx.x, which = blockIdx.y;
    int tid = threadIdx.x, lane = tid & 63, wv = tid >> 6;
    const float* aw = which ? raw_ : caw;
    const float* ab = which ? rab : cab;
    float scale = which ? WG_RGB : 1.0f;
    float* op = which ? s2buf : sbuf;
    __shared__ float wsv[512];
    wsv[tid]       = wsin[(b*2 + which)*512 + tid];
    wsv[tid + 256] = wsin[(b*2 + which)*512 + tid + 256];
    __syncthreads();
    for (int c = wv; c < 512; c += 4) {
        float p = 0.f;
        #pragma unroll
        for (int kk = 0; kk < 8; ++kk)
            p += aw[c*512 + kk*64 + lane] * wsv[kk*64 + lane];
        #pragma unroll
        for (int off = 32; off; off >>= 1) p += __shfl_down(p, off, 64);
        if (lane == 0) op[b*512 + c] = (p + ab[c]) * scale;
    }
}

// ---------------- P2: w2sumT[c][o] = sum_t conv_w[o][c][t]^2 ;  Abf[t][o][c] = bf16(conv_w)
__global__ void k_prepw(const float* __restrict__ conv_w,
                        float* __restrict__ w2sumT, __hip_bfloat16* __restrict__ Abf) {
    int o = blockIdx.x, tid = threadIdx.x;
    #pragma unroll
    for (int j = 0; j < 2; ++j) {
        int c = tid + (j << 8);
        const float* src = conv_w + (o*512 + c)*9;
        float sum = 0.f;
        #pragma unroll
        for (int t = 0; t < 9; ++t) {
            float v = src[t];
            sum += v*v;
            Abf[(t*512 + o)*512 + c] = __float2bfloat16(v);
        }
        w2sumT[c*512 + o] = sum;
    }
}

// ---------------- P3: dcoef[b][o] = rsqrt(sum_c s^2 * w2sumT + 1e-8);  rgbc[b][o3][c] = rgb_w*s2
__global__ void k_dcoef(const float* __restrict__ sbuf, const float* __restrict__ s2buf,
                        const float* __restrict__ w2sumT, const float* __restrict__ rgb_w,
                        float* __restrict__ dcoef, float* __restrict__ rgbc) {
    int b = blockIdx.x, tid = threadIdx.x;
    __shared__ float sq[512];
    #pragma unroll
    for (int j = 0; j < 2; ++j) {
        float v = sbuf[b*512 + tid + (j << 8)];
        sq[tid + (j << 8)] = v*v;
    }
    __syncthreads();
    #pragma unroll
    for (int j = 0; j < 2; ++j) {
        int o = tid + (j << 8);
        float acc = 0.f;
        for (int c = 0; c < 512; ++c) acc += sq[c] * w2sumT[c*512 + o];
        dcoef[b*512 + o] = rsqrtf(acc + 1e-8f);
    }
    #pragma unroll
    for (int j = 0; j < 6; ++j) {
        int idx = tid + (j << 8);          // 0..1535
        int o3 = idx >> 9, c = idx & 511;
        rgbc[b*1536 + idx] = rgb_w[o3*512 + c] * s2buf[b*512 + c];
    }
}

// ---------------- P4: Ypad[b][h+1][w+1][c] = bf16(s[b][c] * const[c][h][w])  (border pre-zeroed)
__global__ void k_ypad(const float* __restrict__ cst, const float* __restrict__ sbuf,
                       __hip_bfloat16* __restrict__ Ypad) {
    int b = blockIdx.x >> 6, h = blockIdx.x & 63, tid = threadIdx.x;
    __shared__ float tile[64][65];
    for (int cc = 0; cc < 8; ++cc) {
        int c0 = cc << 6;
        #pragma unroll
        for (int it = 0; it < 16; ++it) {
            int cl = (it << 2) + (tid >> 6);
            int w = tid & 63;
            tile[cl][w] = cst[(c0 + cl)*4096 + (h << 6) + w];
        }
        __syncthreads();
        #pragma unroll
        for (int it = 0; it < 16; ++it) {
            int flat = (it << 8) + tid;
            int w = flat >> 6, cl = flat & 63;
            float v = sbuf[(b << 9) + c0 + cl] * tile[cl][w];
            Ypad[(((b*66 + h + 1)*66) + (w + 1))*512 + c0 + cl] = __float2bfloat16(v);
        }
        __syncthreads();
    }
}

// ---------------- main conv GEMM: M=512(o) x N=65536(b,hw) x K=9*512, bf16 MFMA 16x16x32
__global__ __launch_bounds__(256) void conv_gemm(
    const short* __restrict__ Abf,   // [9][512][512] bf16
    const short* __restrict__ Ypad,  // [16][66][66][512] bf16
    const float* __restrict__ dcoef, // [16][512]
    const float* __restrict__ noise, // [4096]
    const float* __restrict__ nstr,  // [1]
    const float* __restrict__ bias,  // [512]
    float* __restrict__ xout)        // [16][512][4096]
{
    __shared__ short As[128][40];   // pad 32->40: 80B rows keep 16B align, kill bank conflicts
    __shared__ short Bs[128][40];
    int tid = threadIdx.x;
    int mblk = blockIdx.x & 3;
    int nblk = blockIdx.x >> 2;
    int b  = nblk >> 5;
    int n0 = (nblk & 31) << 7;
    int o0 = mblk << 7;

    int lane = tid & 63;
    int wv = tid >> 6;
    int mw = (wv & 1) << 6;
    int nw = (wv >> 1) << 6;

    f32x4 acc[4][4] = {};

    for (int kk = 0; kk < 144; ++kk) {
        int t = kk >> 4;
        int c0 = (kk & 15) << 5;
        int dh = t / 3, dw = t - dh*3;
        #pragma unroll
        for (int j = 0; j < 2; ++j) {
            int flat = tid + (j << 8);
            int row = flat >> 2;
            int cs = (flat & 3) << 3;
            short8 av = *(const short8*)(Abf + ((t << 9) + o0 + row)*512 + c0 + cs);
            int n = n0 + row;
            int hp = (n >> 6) + dh;
            int wp = (n & 63) + dw;
            short8 bv = *(const short8*)(Ypad + ((((b*66 + hp)*66) + wp) << 9) + c0 + cs);
            *(short8*)&As[row][cs] = av;
            *(short8*)&Bs[row][cs] = bv;
        }
        __syncthreads();
        short8 af[4], bfr[4];
        int k8 = (lane >> 4) << 3;
        int mr = mw + (lane & 15);
        int nr = nw + (lane & 15);
        #pragma unroll
        for (int i = 0; i < 4; ++i) {
            af[i]  = *(const short8*)&As[mr + i*16][k8];
            bfr[i] = *(const short8*)&Bs[nr + i*16][k8];
        }
        #pragma unroll
        for (int mi = 0; mi < 4; ++mi)
            #pragma unroll
            for (int ni = 0; ni < 4; ++ni)
                acc[mi][ni] = __builtin_amdgcn_mfma_f32_16x16x32_bf16(af[mi], bfr[ni], acc[mi][ni], 0, 0, 0);
        __syncthreads();
    }

    float ns = nstr[0];
    #pragma unroll
    for (int mi = 0; mi < 4; ++mi) {
        int ob = o0 + mw + mi*16 + ((lane >> 4) << 2);
        f32x4 dc = *(const f32x4*)(dcoef + (b << 9) + ob);
        f32x4 bs4 = *(const f32x4*)(bias + ob);
        #pragma unroll
        for (int ni = 0; ni < 4; ++ni) {
            int hw = n0 + nw + ni*16 + (lane & 15);
            float nz = noise[hw] * ns;
            #pragma unroll
            for (int r = 0; r < 4; ++r) {
                float v = acc[mi][ni][r] * dc[r] + nz + bs4[r];
                v = (v < 0.0f ? LRELU_SLOPE * v : v) * ACT_GAIN;
                xout[(((b << 9) + ob + r) << 12) + hw] = v;
            }
        }
    }
}

// ---------------- ToRGB: img[b][o3][hw] = sum_c x[b][c][hw]*rgbc[b][o3][c] + rgb_b[o3]
__global__ void k_torgb(const float* __restrict__ x, const float* __restrict__ rgbc,
                        const float* __restrict__ rgb_b, float* __restrict__ img) {
    int g = blockIdx.x * 256 + threadIdx.x;
    int b = g >> 12, hw = g & 4095;
    const float* xb = x + ((b << 9) << 12) + hw;
    const float* rc = rgbc + b*1536;
    float a0 = 0.f, a1 = 0.f, a2 = 0.f;
    #pragma unroll 4
    for (int c = 0; c < 512; ++c) {
        float xv = xb[c << 12];
        a0 += xv * rc[c];
        a1 += xv * rc[512 + c];
        a2 += xv * rc[1024 + c];
    }
    float* ip = img + ((b*3) << 12) + hw;
    ip[0]         = a0 + rgb_b[0];
    ip[1 << 12]   = a1 + rgb_b[1];
    ip[2 << 12]   = a2 + rgb_b[2];
}

extern "C" void kernel_launch(void* const* d_in, const int* in_sizes, int n_in,
                              void* d_out, int out_size, void* d_ws, size_t ws_size,
                              hipStream_t stream) {
    (void)in_sizes; (void)n_in; (void)out_size; (void)ws_size;
    const float* wsin   = (const float*)d_in[0];   // [16][2][512]
    const float* cst    = (const float*)d_in[1];   // [512][64][64]
    const float* conv_w = (const float*)d_in[2];   // [512][512][3][3]
    const float* conv_b = (const float*)d_in[3];   // [512]
    const float* caw    = (const float*)d_in[4];   // [512][512]
    const float* cab    = (const float*)d_in[5];   // [512]
    const float* noise  = (const float*)d_in[6];   // [64][64]
    const float* nstr   = (const float*)d_in[7];   // [1]
    const float* rgb_w  = (const float*)d_in[8];   // [3][512][1][1]
    const float* rgb_b  = (const float*)d_in[9];   // [3]
    const float* raw_   = (const float*)d_in[10];  // [512][512]
    const float* rab    = (const float*)d_in[11];  // [512]

    char* wsb = (char*)d_ws;
    float* sbuf   = (float*)(wsb + 0);         // 16*512 f32
    float* s2buf  = (float*)(wsb + 32768);     // 16*512 f32
    float* dcoef  = (float*)(wsb + 65536);     // 16*512 f32
    float* rgbc   = (float*)(wsb + 98304);     // 16*3*512 f32
    float* w2sumT = (float*)(wsb + 196608);    // 512*512 f32
    __hip_bfloat16* Abf  = (__hip_bfloat16*)(wsb + 1245184);  // 9*512*512 bf16
    __hip_bfloat16* Ypad = (__hip_bfloat16*)(wsb + 5963776);  // 16*66*66*512 bf16

    float* xout = (float*)d_out;               // [16][512][4096]
    float* img  = xout + 33554432;             // [16][3][4096]

    hipMemsetAsync(Ypad, 0, 71368704, stream);
    k_styles<<<dim3(16, 2), 256, 0, stream>>>(wsin, caw, cab, raw_, rab, sbuf, s2buf);
    k_prepw<<<512, 256, 0, stream>>>(conv_w, w2sumT, Abf);
    k_dcoef<<<16, 256, 0, stream>>>(sbuf, s2buf, w2sumT, rgb_w, dcoef, rgbc);
    k_ypad<<<1024, 256, 0, stream>>>(cst, sbuf, Ypad);
    conv_gemm<<<2048, 256, 0, stream>>>((const short*)Abf, (const short*)Ypad,
                                        dcoef, noise, nstr, conv_b, xout);
    k_torgb<<<256, 256, 0, stream>>>(xout, rgbc, rgb_b, img);
}

// Round 2
// 720.085 us; speedup vs baseline: 1.1881x; 1.1881x over previous
//
#include <hip/hip_runtime.h>
#include <hip/hip_bf16.h>

typedef __attribute__((ext_vector_type(8))) short short8;
typedef __attribute__((ext_vector_type(4))) float f32x4;

#define LRELU_SLOPE 0.2f
#define ACT_GAIN 1.41421356237309515f
#define WG_RGB 0.04419417382415922f   // 1/sqrt(512)

__device__ __forceinline__ void glds16(const short* g, short* l) {
    __builtin_amdgcn_global_load_lds(
        (const __attribute__((address_space(1))) unsigned int*)g,
        (__attribute__((address_space(3))) unsigned int*)l, 16, 0, 0);
}

// ---------------- P1: styles  s = ws[:,0]@caw^T + cab ;  s2 = (ws[:,1]@raw^T + rab)*wg
__global__ void k_styles(const float* __restrict__ wsin,
                         const float* __restrict__ caw, const float* __restrict__ cab,
                         const float* __restrict__ raw_, const float* __restrict__ rab,
                         float* __restrict__ sbuf, float* __restrict__ s2buf) {
    int b = blockIdx.x, which = blockIdx.y;
    int tid = threadIdx.x, lane = tid & 63, wv = tid >> 6;
    const float* aw = which ? raw_ : caw;
    const float* ab = which ? rab : cab;
    float scale = which ? WG_RGB : 1.0f;
    float* op = which ? s2buf : sbuf;
    __shared__ float wsv[512];
    wsv[tid]       = wsin[(b*2 + which)*512 + tid];
    wsv[tid + 256] = wsin[(b*2 + which)*512 + tid + 256];
    __syncthreads();
    for (int c = wv; c < 512; c += 4) {
        float p = 0.f;
        #pragma unroll
        for (int kk = 0; kk < 8; ++kk)
            p += aw[c*512 + kk*64 + lane] * wsv[kk*64 + lane];
        #pragma unroll
        for (int off = 32; off; off >>= 1) p += __shfl_down(p, off, 64);
        if (lane == 0) op[b*512 + c] = (p + ab[c]) * scale;
    }
}

// ---------------- P2: w2sum[o][c] = sum_t conv_w[o][c][t]^2 ;  Abf[t][o][c] = bf16(conv_w)
__global__ void k_prepw(const float* __restrict__ conv_w,
                        float* __restrict__ w2sum, __hip_bfloat16* __restrict__ Abf) {
    int o = blockIdx.x, tid = threadIdx.x;
    #pragma unroll
    for (int j = 0; j < 2; ++j) {
        int c = tid + (j << 8);
        const float* src = conv_w + (o*512 + c)*9;
        float sum = 0.f;
        #pragma unroll
        for (int t = 0; t < 9; ++t) {
            float v = src[t];
            sum += v*v;
            Abf[(t*512 + o)*512 + c] = __float2bfloat16(v);
        }
        w2sum[o*512 + c] = sum;
    }
}

// ---------------- P3: dcoef[b][o] = rsqrt(sum_c s^2 * w2sum[o][c] + 1e-8)  (1 wave per (b,o))
__global__ __launch_bounds__(256) void k_dcoef(const float* __restrict__ sbuf,
                                               const float* __restrict__ w2sum,
                                               float* __restrict__ dcoef) {
    int gw = blockIdx.x*4 + (threadIdx.x >> 6);
    int lane = threadIdx.x & 63;
    int b = gw >> 9, o = gw & 511;
    float acc = 0.f;
    #pragma unroll
    for (int i = 0; i < 8; ++i) {
        int c = (i << 6) + lane;
        float sv = sbuf[(b << 9) + c];
        acc += sv*sv*w2sum[(o << 9) + c];
    }
    #pragma unroll
    for (int off = 32; off; off >>= 1) acc += __shfl_down(acc, off, 64);
    if (lane == 0) dcoef[(b << 9) + o] = rsqrtf(acc + 1e-8f);
}

// ---------------- P4a: zero only the Ypad border (replaces 71MB memset)
__global__ void k_border(__hip_bfloat16* __restrict__ Ypad) {
    int blk = blockIdx.x;
    int b = blk / 260;
    int cell = blk - b*260;
    int h, w;
    if (cell < 66)       { h = 0;          w = cell; }
    else if (cell < 132) { h = 65;         w = cell - 66; }
    else if (cell < 196) { h = cell - 131; w = 0; }
    else                 { h = cell - 195; w = 65; }
    short8* p = (short8*)((short*)Ypad + (((b*66 + h)*66) + w)*512);
    short8 z = {};
    p[threadIdx.x] = z;
}

// ---------------- P4b: Ypad[b][h+1][w+1][c] = bf16(s[b][c] * const[c][h][w])  (interior)
__global__ void k_ypad(const float* __restrict__ cst, const float* __restrict__ sbuf,
                       __hip_bfloat16* __restrict__ Ypad) {
    int b = blockIdx.x >> 6, h = blockIdx.x & 63, tid = threadIdx.x;
    __shared__ float tile[64][65];
    for (int cc = 0; cc < 8; ++cc) {
        int c0 = cc << 6;
        #pragma unroll
        for (int it = 0; it < 16; ++it) {
            int cl = (it << 2) + (tid >> 6);
            int w = tid & 63;
            tile[cl][w] = cst[(c0 + cl)*4096 + (h << 6) + w];
        }
        __syncthreads();
        #pragma unroll
        for (int it = 0; it < 16; ++it) {
            int flat = (it << 8) + tid;
            int w = flat >> 6, cl = flat & 63;
            float v = sbuf[(b << 9) + c0 + cl] * tile[cl][w];
            Ypad[(((b*66 + h + 1)*66) + (w + 1))*512 + c0 + cl] = __float2bfloat16(v);
        }
        __syncthreads();
    }
}

// ---------------- main conv GEMM: M=512(o) x N=65536(b,hw) x K=9*512, bf16 MFMA 16x16x32
// global_load_lds(width=16) staging into XOR-swizzled LDS; XCD-aware block swizzle.
__global__ __launch_bounds__(256) void conv_gemm(
    const short* __restrict__ Abf,   // [9][512][512] bf16
    const short* __restrict__ Ypad,  // [16][66][66][512] bf16
    const float* __restrict__ dcoef, // [16][512]
    const float* __restrict__ noise, // [4096]
    const float* __restrict__ nstr,  // [1]
    const float* __restrict__ bias,  // [512]
    float* __restrict__ xout)        // [16][512][4096]
{
    // logical [128 rows][32 k-shorts]; chunk q (8 shorts) of row r stored at
    // slot q ^ ((r>>1)&3)  -> ds_read_b128 frag reads are 2-way (free)
    __shared__ short As[8][512];
    __shared__ short Bs[8][512];
    int tid = threadIdx.x;
    int lane = tid & 63, wv = tid >> 6;

    // XCD swizzle: each XCD sees one mblk -> A-tile stays L2-resident
    int blk = blockIdx.x;
    int xcd = blk & 7;
    int idx = blk >> 3;
    int mblk = xcd & 3;
    int nblk = idx | ((xcd >> 2) << 8);
    int b  = nblk >> 5;
    int n0 = (nblk & 31) << 7;
    int o0 = mblk << 7;

    // staging lane constants: lane L loads chunk q=(L&3)^((L>>3)&3) of tile-row 16j+(L>>2)
    int lrow = lane >> 2;
    int q8 = ((lane & 3) ^ ((lane >> 3) & 3)) << 3;
    int aOff0 = ((o0 + (wv << 5) + lrow) << 9) + q8;
    int aOff1 = aOff0 + (16 << 9);
    int nA = n0 + (wv << 5) + lrow;
    int nB = nA + 16;
    short* ldsA = (short*)As + (wv << 10);
    short* ldsB = (short*)Bs + (wv << 10);

    int quad = lane >> 4;
    int ml = lane & 15;
    int sa = (quad ^ ((lane >> 1) & 3)) << 3;   // frag-read swizzled slot
    int mw = (wv & 1) << 6;
    int nw = (wv >> 1) << 6;

    f32x4 acc[4][4] = {};

    for (int t = 0; t < 9; ++t) {
        int dh = (t * 11) >> 5;                 // t/3
        int dw = t - dh * 3;
        const short* At = Abf + (t << 18);
        int bOff0 = (((b*66 + (nA >> 6) + dh)*66) + (nA & 63) + dw)*512 + q8;
        int bOff1 = (((b*66 + (nB >> 6) + dh)*66) + (nB & 63) + dw)*512 + q8;
        for (int c0 = 0; c0 < 512; c0 += 32) {
            glds16(At + aOff0 + c0, ldsA);
            glds16(At + aOff1 + c0, ldsA + 512);
            glds16(Ypad + bOff0 + c0, ldsB);
            glds16(Ypad + bOff1 + c0, ldsB + 512);
            __syncthreads();
            short8 af[4], bf[4];
            #pragma unroll
            for (int i = 0; i < 4; ++i) {
                af[i] = *(const short8*)((const short*)As + ((mw + ml + (i << 4)) << 5) + sa);
                bf[i] = *(const short8*)((const short*)Bs + ((nw + ml + (i << 4)) << 5) + sa);
            }
            #pragma unroll
            for (int mi = 0; mi < 4; ++mi)
                #pragma unroll
                for (int ni = 0; ni < 4; ++ni)
                    acc[mi][ni] = __builtin_amdgcn_mfma_f32_16x16x32_bf16(af[mi], bf[ni], acc[mi][ni], 0, 0, 0);
            __syncthreads();
        }
    }

    float ns = nstr[0];
    #pragma unroll
    for (int mi = 0; mi < 4; ++mi) {
        int ob = o0 + mw + mi*16 + (quad << 2);
        f32x4 dc  = *(const f32x4*)(dcoef + (b << 9) + ob);
        f32x4 bs4 = *(const f32x4*)(bias + ob);
        #pragma unroll
        for (int ni = 0; ni < 4; ++ni) {
            int hw = n0 + nw + ni*16 + ml;
            float nz = noise[hw] * ns;
            #pragma unroll
            for (int r = 0; r < 4; ++r) {
                float v = acc[mi][ni][r] * dc[r] + nz + bs4[r];
                v = (v < 0.0f ? LRELU_SLOPE * v : v) * ACT_GAIN;
                xout[(((b << 9) + ob + r) << 12) + hw] = v;
            }
        }
    }
}

// ---------------- ToRGB: img[b][o3][hw] = sum_c x[b][c][hw]*rgb_w[o3][c]*s2[b][c] + rgb_b[o3]
__global__ __launch_bounds__(256) void k_torgb(const float* __restrict__ x,
                                               const float* __restrict__ s2buf,
                                               const float* __restrict__ rgb_w,
                                               const float* __restrict__ rgb_b,
                                               float* __restrict__ img) {
    int b = blockIdx.x >> 6;
    int hw0 = (blockIdx.x & 63) << 6;
    int lane = threadIdx.x & 63, wv = threadIdx.x >> 6;
    const float* xb = x + (b << 21) + ((wv << 7) << 12) + hw0 + lane;
    const float* s2 = s2buf + (b << 9) + (wv << 7);
    const float* rw = rgb_w + (wv << 7);
    float a0 = 0.f, a1 = 0.f, a2 = 0.f;
    #pragma unroll 8
    for (int cc = 0; cc < 128; ++cc) {
        float xv = xb[cc << 12];
        float sv = s2[cc];
        float xs = xv * sv;
        a0 += xs * rw[cc];
        a1 += xs * rw[512 + cc];
        a2 += xs * rw[1024 + cc];
    }
    __shared__ float red[4][3][64];
    red[wv][0][lane] = a0; red[wv][1][lane] = a1; red[wv][2][lane] = a2;
    __syncthreads();
    if (threadIdx.x < 192) {
        int o3 = threadIdx.x >> 6, l = threadIdx.x & 63;
        float s = red[0][o3][l] + red[1][o3][l] + red[2][o3][l] + red[3][o3][l] + rgb_b[o3];
        img[((b*3 + o3) << 12) + hw0 + l] = s;
    }
}

extern "C" void kernel_launch(void* const* d_in, const int* in_sizes, int n_in,
                              void* d_out, int out_size, void* d_ws, size_t ws_size,
                              hipStream_t stream) {
    (void)in_sizes; (void)n_in; (void)out_size; (void)ws_size;
    const float* wsin   = (const float*)d_in[0];   // [16][2][512]
    const float* cst    = (const float*)d_in[1];   // [512][64][64]
    const float* conv_w = (const float*)d_in[2];   // [512][512][3][3]
    const float* conv_b = (const float*)d_in[3];   // [512]
    const float* caw    = (const float*)d_in[4];   // [512][512]
    const float* cab    = (const float*)d_in[5];   // [512]
    const float* noise  = (const float*)d_in[6];   // [64][64]
    const float* nstr   = (const float*)d_in[7];   // [1]
    const float* rgb_w  = (const float*)d_in[8];   // [3][512][1][1]
    const float* rgb_b  = (const float*)d_in[9];   // [3]
    const float* raw_   = (const float*)d_in[10];  // [512][512]
    const float* rab    = (const float*)d_in[11];  // [512]

    char* wsb = (char*)d_ws;
    float* sbuf   = (float*)(wsb + 0);         // 16*512 f32
    float* s2buf  = (float*)(wsb + 32768);     // 16*512 f32
    float* dcoef  = (float*)(wsb + 65536);     // 16*512 f32
    float* w2sum  = (float*)(wsb + 196608);    // 512*512 f32 ([o][c])
    __hip_bfloat16* Abf  = (__hip_bfloat16*)(wsb + 1245184);  // 9*512*512 bf16
    __hip_bfloat16* Ypad = (__hip_bfloat16*)(wsb + 5963776);  // 16*66*66*512 bf16

    float* xout = (float*)d_out;               // [16][512][4096]
    float* img  = xout + 33554432;             // [16][3][4096]

    k_border<<<4160, 64, 0, stream>>>(Ypad);
    k_styles<<<dim3(16, 2), 256, 0, stream>>>(wsin, caw, cab, raw_, rab, sbuf, s2buf);
    k_prepw<<<512, 256, 0, stream>>>(conv_w, w2sum, Abf);
    k_dcoef<<<2048, 256, 0, stream>>>(sbuf, w2sum, dcoef);
    k_ypad<<<1024, 256, 0, stream>>>(cst, sbuf, Ypad);
    conv_gemm<<<2048, 256, 0, stream>>>((const short*)Abf, (const short*)Ypad,
                                        dcoef, noise, nstr, conv_b, xout);
    k_torgb<<<1024, 256, 0, stream>>>(xout, s2buf, rgb_w, rgb_b, img);
}

// Round 5
// 600.028 us; speedup vs baseline: 1.4258x; 1.2001x over previous
//
#include <hip/hip_runtime.h>
#include <hip/hip_bf16.h>

typedef __attribute__((ext_vector_type(8))) short short8;
typedef __attribute__((ext_vector_type(4))) float f32x4;

#define LRELU_SLOPE 0.2f
#define ACT_GAIN 1.41421356237309515f
#define WG_RGB 0.04419417382415922f   // 1/sqrt(512)

__device__ __forceinline__ void glds16(const short* g, short* l) {
    __builtin_amdgcn_global_load_lds(
        (const __attribute__((address_space(1))) unsigned int*)g,
        (__attribute__((address_space(3))) unsigned int*)l, 16, 0, 0);
}

// ---------------- P0: zero Ypad border + init img to rgb_b
__global__ void k_init(__hip_bfloat16* __restrict__ Ypad,
                       const float* __restrict__ rgb_b, float* __restrict__ img) {
    int blk = blockIdx.x, tid = threadIdx.x;
    if (blk < 1040) {                       // border: 4160 slots, 4 per block
        int gslot = blk*4 + (tid >> 6);
        int b = gslot / 260;
        int cell = gslot - b*260;
        int h, w;
        if (cell < 66)       { h = 0;          w = cell; }
        else if (cell < 132) { h = 65;         w = cell - 66; }
        else if (cell < 196) { h = cell - 131; w = 0; }
        else                 { h = cell - 195; w = 65; }
        short8 z = {};
        *(short8*)((short*)Ypad + (((b*66 + h)*66) + w)*512 + (tid & 63)*8) = z;
    } else {                                // img init: 48 blocks x 4 f32x4 (49152 f32x4 total)
        int blk2 = blk - 1040;
        #pragma unroll
        for (int j = 0; j < 4; ++j) {
            int f4 = blk2*1024 + j*256 + tid;   // 0..49151 (f32x4 units)
            int b3 = f4 >> 10;                  // plane = 1024 f32x4
            int o3 = b3 % 3;
            float v = rgb_b[o3];
            f32x4 vv = {v, v, v, v};
            *(f32x4*)(img + f4*4) = vv;
        }
    }
}

// ---------------- P1: styles  s = ws[:,0]@caw^T + cab ;  s2 = (ws[:,1]@raw^T + rab)*wg
__global__ void k_styles(const float* __restrict__ wsin,
                         const float* __restrict__ caw, const float* __restrict__ cab,
                         const float* __restrict__ raw_, const float* __restrict__ rab,
                         float* __restrict__ sbuf, float* __restrict__ s2buf) {
    int b = blockIdx.x, which = blockIdx.y;
    int tid = threadIdx.x, lane = tid & 63, wv = tid >> 6;
    const float* aw = which ? raw_ : caw;
    const float* ab = which ? rab : cab;
    float scale = which ? WG_RGB : 1.0f;
    float* op = which ? s2buf : sbuf;
    __shared__ float wsv[512];
    wsv[tid]       = wsin[(b*2 + which)*512 + tid];
    wsv[tid + 256] = wsin[(b*2 + which)*512 + tid + 256];
    __syncthreads();
    for (int c = wv; c < 512; c += 4) {
        float p = 0.f;
        #pragma unroll
        for (int kk = 0; kk < 8; ++kk)
            p += aw[c*512 + kk*64 + lane] * wsv[kk*64 + lane];
        #pragma unroll
        for (int off = 32; off; off >>= 1) p += __shfl_down(p, off, 64);
        if (lane == 0) op[b*512 + c] = (p + ab[c]) * scale;
    }
}

// ---------------- P2: w2sum[o][c] = sum_t conv_w[o][c][t]^2 ;  Abf[t][o][c] = bf16(conv_w)
__global__ __launch_bounds__(256) void k_prepw(const float* __restrict__ conv_w,
                        float* __restrict__ w2sum, __hip_bfloat16* __restrict__ Abf) {
    int o = blockIdx.x, tid = threadIdx.x;
    __shared__ float wrow[4608];
    const f32x4* src = (const f32x4*)(conv_w + o*4608);
    #pragma unroll
    for (int r = 0; r < 5; ++r) {
        int idx = tid + (r << 8);
        if (idx < 1152) *(f32x4*)&wrow[idx*4] = src[idx];
    }
    __syncthreads();
    #pragma unroll
    for (int j = 0; j < 2; ++j) {
        int c = tid + (j << 8);
        float sum = 0.f;
        #pragma unroll
        for (int t = 0; t < 9; ++t) {
            float v = wrow[c*9 + t];
            sum += v*v;
            Abf[(t*512 + o)*512 + c] = __float2bfloat16(v);
        }
        w2sum[o*512 + c] = sum;
    }
}

// ---------------- P3: dcoef (1 wave per (b,o)) + rgbc[b][o3][c] on first 96 blocks
__global__ __launch_bounds__(256) void k_dcoef(const float* __restrict__ sbuf,
                                               const float* __restrict__ w2sum,
                                               const float* __restrict__ s2buf,
                                               const float* __restrict__ rgb_w,
                                               float* __restrict__ dcoef,
                                               float* __restrict__ rgbc) {
    int gw = blockIdx.x*4 + (threadIdx.x >> 6);
    int lane = threadIdx.x & 63;
    int b = gw >> 9, o = gw & 511;
    float acc = 0.f;
    #pragma unroll
    for (int i = 0; i < 8; ++i) {
        int c = (i << 6) + lane;
        float sv = sbuf[(b << 9) + c];
        acc += sv*sv*w2sum[(o << 9) + c];
    }
    #pragma unroll
    for (int off = 32; off; off >>= 1) acc += __shfl_down(acc, off, 64);
    if (lane == 0) dcoef[(b << 9) + o] = rsqrtf(acc + 1e-8f);
    if (blockIdx.x < 96) {
        int flat = blockIdx.x*256 + threadIdx.x;   // = b*1536 + o3*512 + c
        int bb = flat / 1536;
        int r  = flat - bb*1536;
        int c  = r & 511;
        rgbc[flat] = rgb_w[r] * s2buf[bb*512 + c];
    }
}

// ---------------- P4: Ypad[b][h+1][w+1][c] = bf16(s[b][c] * const[c][h][w])  (interior)
__global__ void k_ypad(const float* __restrict__ cst, const float* __restrict__ sbuf,
                       __hip_bfloat16* __restrict__ Ypad) {
    int b = blockIdx.x >> 6, h = blockIdx.x & 63, tid = threadIdx.x;
    __shared__ float tile[64][65];
    for (int cc = 0; cc < 8; ++cc) {
        int c0 = cc << 6;
        #pragma unroll
        for (int it = 0; it < 16; ++it) {
            int cl = (it << 2) + (tid >> 6);
            int w = tid & 63;
            tile[cl][w] = cst[(c0 + cl)*4096 + (h << 6) + w];
        }
        __syncthreads();
        #pragma unroll
        for (int it = 0; it < 16; ++it) {
            int flat = (it << 8) + tid;
            int w = flat >> 6, cl = flat & 63;
            float v = sbuf[(b << 9) + c0 + cl] * tile[cl][w];
            Ypad[(((b*66 + h + 1)*66) + (w + 1))*512 + c0 + cl] = __float2bfloat16(v);
        }
        __syncthreads();
    }
}

// ---------------- main conv GEMM with tap-reuse B-halo staging + fused ToRGB
// M=512(o) x N=65536(b,hw) x K=9*512. Per c-chunk(32): B-halo staged ONCE for
// all 9 taps; A staged 3 taps at a time. 48 MFMAs per barrier-pair.
__global__ __launch_bounds__(256) void conv_gemm(
    const short* __restrict__ Abf,   // [9][512][512] bf16
    const short* __restrict__ Ypad,  // [16][66][66][512] bf16
    const float* __restrict__ dcoef, // [16][512]
    const float* __restrict__ noise, // [4096]
    const float* __restrict__ nstr,  // [1]
    const float* __restrict__ bias,  // [512]
    const float* __restrict__ rgbc,  // [16][3][512]
    float* __restrict__ xout,        // [16][512][4096]
    float* __restrict__ img)         // [16][3][4096], pre-init to rgb_b
{
    __shared__ short Bh[8448];        // [264 pos = 4h x 66w][32 c], XOR-swizzled
    __shared__ short A3[12288];       // [3 tap][128 row][32 c], XOR-swizzled
    __shared__ float red[128][3][2];  // ToRGB partials [hwl][o3][m-half]
    int tid = threadIdx.x, lane = tid & 63, wv = tid >> 6;

    int blk = blockIdx.x;
    int xcd = blk & 7, idx = blk >> 3;
    int mblk = xcd & 3;
    int nblk = idx | ((xcd >> 2) << 8);
    int b  = nblk >> 5;
    int n0 = (nblk & 31) << 7;
    int o0 = mblk << 7;
    int h0 = n0 >> 6;                 // top of 4-row halo window in padded coords

    // B-halo staging constants: 1056 16B-slots, 5 rounds (last: 32 lanes)
    int bgofs[5];
    #pragma unroll
    for (int r = 0; r < 5; ++r) {
        int i = tid + (r << 8);
        int p = i >> 2;
        int hl = p / 66;
        int w  = p - hl*66;
        int q  = (i & 3) ^ ((p >> 1) & 3);
        bgofs[r] = (((b*66 + h0 + hl)*66) + w)*512 + q*8;
    }
    // A3 staging constants: 24 slots (1KB each), 6 rounds x 4 waves
    int agofs[6];
    #pragma unroll
    for (int r = 0; r < 6; ++r) {
        int s = r*4 + wv;
        int tl = s >> 3;
        int row = ((s & 7) << 4) + (lane >> 2);
        int q = (lane & 3) ^ ((lane >> 3) & 3);
        agofs[r] = (tl << 18) + ((o0 + row) << 9) + q*8;
    }

    int quad = lane >> 4, ml = lane & 15;
    int sa = (quad ^ ((ml >> 1) & 3)) << 3;
    int mw = (wv & 1) << 6, nw = (wv >> 1) << 6;
    int nh = nw >> 6;
    short* ldsB = Bh + (tid & ~63)*8;        // wave-uniform bases
    short* ldsA = A3 + wv*512;

    f32x4 acc[4][4] = {};

    for (int c0 = 0; c0 < 512; c0 += 32) {
        #pragma unroll
        for (int r = 0; r < 4; ++r)
            glds16(Ypad + bgofs[r] + c0, ldsB + (r << 11));
        if (tid < 32)
            glds16(Ypad + bgofs[4] + c0, Bh + 8192);
        #pragma unroll
        for (int r = 0; r < 6; ++r)
            glds16(Abf + agofs[r] + c0, ldsA + (r << 11));
        __syncthreads();
        for (int dh = 0; dh < 3; ++dh) {
            #pragma unroll
            for (int tl = 0; tl < 3; ++tl) {
                short8 af[4], bf[4];
                int pb = (nh + dh)*66 + ml + tl;
                int swz = (quad ^ ((pb >> 1) & 3)) << 3;
                #pragma unroll
                for (int i = 0; i < 4; ++i) {
                    af[i] = *(const short8*)(A3 + tl*4096 + (mw + ml + i*16)*32 + sa);
                    bf[i] = *(const short8*)(Bh + (pb + i*16)*32 + swz);
                }
                #pragma unroll
                for (int mi = 0; mi < 4; ++mi)
                    #pragma unroll
                    for (int ni = 0; ni < 4; ++ni)
                        acc[mi][ni] = __builtin_amdgcn_mfma_f32_16x16x32_bf16(af[mi], bf[ni], acc[mi][ni], 0, 0, 0);
            }
            if (dh < 2) {
                __syncthreads();
                #pragma unroll
                for (int r = 0; r < 6; ++r)
                    glds16(Abf + (((dh + 1)*3) << 18) + agofs[r] + c0, ldsA + (r << 11));
                __syncthreads();
            }
        }
        __syncthreads();
    }

    // ---------------- epilogue: demod + noise + bias + lrelu + store + fused ToRGB
    float ns = nstr[0];
    float pr[4][3] = {};
    #pragma unroll
    for (int mi = 0; mi < 4; ++mi) {
        int ob = o0 + mw + mi*16 + (quad << 2);
        f32x4 dc  = *(const f32x4*)(dcoef + (b << 9) + ob);
        f32x4 bs4 = *(const f32x4*)(bias + ob);
        f32x4 rc0 = *(const f32x4*)(rgbc + b*1536 + ob);
        f32x4 rc1 = *(const f32x4*)(rgbc + b*1536 + 512 + ob);
        f32x4 rc2 = *(const f32x4*)(rgbc + b*1536 + 1024 + ob);
        #pragma unroll
        for (int ni = 0; ni < 4; ++ni) {
            int hw = n0 + nw + ni*16 + ml;
            float nz = noise[hw] * ns;
            #pragma unroll
            for (int r = 0; r < 4; ++r) {
                float v = acc[mi][ni][r] * dc[r] + nz + bs4[r];
                v = (v < 0.0f ? LRELU_SLOPE * v : v) * ACT_GAIN;
                xout[(((b << 9) + ob + r) << 12) + hw] = v;
                pr[ni][0] += v * rc0[r];
                pr[ni][1] += v * rc1[r];
                pr[ni][2] += v * rc2[r];
            }
        }
    }
    #pragma unroll
    for (int ni = 0; ni < 4; ++ni)
        #pragma unroll
        for (int o3 = 0; o3 < 3; ++o3) {
            float v = pr[ni][o3];
            v += __shfl_down(v, 16, 64);
            v += __shfl_down(v, 32, 64);
            pr[ni][o3] = v;
        }
    if (lane < 16) {
        #pragma unroll
        for (int ni = 0; ni < 4; ++ni)
            #pragma unroll
            for (int o3 = 0; o3 < 3; ++o3)
                red[nw + ni*16 + ml][o3][wv & 1] = pr[ni][o3];
    }
    __syncthreads();
    // 384 (o3,hwl) pairs, 256 threads: strided loop (round-4 bug was tid<384 with 256 threads)
    for (int p = tid; p < 384; p += 256) {
        int o3 = p >> 7, hwl = p & 127;
        float v = red[hwl][o3][0] + red[hwl][o3][1];
        atomicAdd(img + ((b*3 + o3) << 12) + n0 + hwl, v);
    }
}

extern "C" void kernel_launch(void* const* d_in, const int* in_sizes, int n_in,
                              void* d_out, int out_size, void* d_ws, size_t ws_size,
                              hipStream_t stream) {
    (void)in_sizes; (void)n_in; (void)out_size; (void)ws_size;
    const float* wsin   = (const float*)d_in[0];   // [16][2][512]
    const float* cst    = (const float*)d_in[1];   // [512][64][64]
    const float* conv_w = (const float*)d_in[2];   // [512][512][3][3]
    const float* conv_b = (const float*)d_in[3];   // [512]
    const float* caw    = (const float*)d_in[4];   // [512][512]
    const float* cab    = (const float*)d_in[5];   // [512]
    const float* noise  = (const float*)d_in[6];   // [64][64]
    const float* nstr   = (const float*)d_in[7];   // [1]
    const float* rgb_w  = (const float*)d_in[8];   // [3][512][1][1]
    const float* rgb_b  = (const float*)d_in[9];   // [3]
    const float* raw_   = (const float*)d_in[10];  // [512][512]
    const float* rab    = (const float*)d_in[11];  // [512]

    char* wsb = (char*)d_ws;
    float* sbuf   = (float*)(wsb + 0);         // 16*512 f32
    float* s2buf  = (float*)(wsb + 32768);     // 16*512 f32
    float* dcoef  = (float*)(wsb + 65536);     // 16*512 f32
    float* rgbc   = (float*)(wsb + 98304);     // 16*3*512 f32
    float* w2sum  = (float*)(wsb + 196608);    // 512*512 f32 ([o][c])
    __hip_bfloat16* Abf  = (__hip_bfloat16*)(wsb + 1245184);  // 9*512*512 bf16
    __hip_bfloat16* Ypad = (__hip_bfloat16*)(wsb + 5963776);  // 16*66*66*512 bf16

    float* xout = (float*)d_out;               // [16][512][4096]
    float* img  = xout + 33554432;             // [16][3][4096]

    k_init<<<1088, 256, 0, stream>>>(Ypad, rgb_b, img);
    k_styles<<<dim3(16, 2), 256, 0, stream>>>(wsin, caw, cab, raw_, rab, sbuf, s2buf);
    k_prepw<<<512, 256, 0, stream>>>(conv_w, w2sum, Abf);
    k_dcoef<<<2048, 256, 0, stream>>>(sbuf, w2sum, s2buf, rgb_w, dcoef, rgbc);
    k_ypad<<<1024, 256, 0, stream>>>(cst, sbuf, Ypad);
    conv_gemm<<<2048, 256, 0, stream>>>((const short*)Abf, (const short*)Ypad,
                                        dcoef, noise, nstr, conv_b, rgbc, xout, img);
}